// Round 13
// baseline (266.216 us; speedup 1.0000x reference)
//
#include <hip/hip_runtime.h>
#include <hip/hip_bf16.h>
#include <stdint.h>

// Problem constants
#define NH 12
#define DHD 64
#define DM 768
#define NB 2
#define SS 4096
#define MTOK 8192  // NB*SS

typedef __attribute__((ext_vector_type(8))) short short8;
typedef __attribute__((ext_vector_type(4))) float f32x4;
typedef __attribute__((ext_vector_type(16))) float f32x16;
typedef __attribute__((ext_vector_type(4))) unsigned short ushort4v;
typedef __attribute__((ext_vector_type(4))) unsigned int uint4v;

#define MFMA16(a, b, c) __builtin_amdgcn_mfma_f32_16x16x32_bf16(a, b, c, 0, 0, 0)
#define MFMA32(a, b, c) __builtin_amdgcn_mfma_f32_32x32x16_bf16(a, b, c, 0, 0, 0)

// Q is pre-scaled by SCALE*log2(e) so softmax works in exp2 domain.
#define QSCALE 0.18033688f  // 0.125 * 1.4426950408889634

#define CVTPK(d, a, b) asm("v_cvt_pk_bf16_f32 %0, %1, %2" : "=v"(d) : "v"(a), "v"(b))
// v_permlane32_swap_b32 vdst, vsrc : vdst.hi-lanes <-> vsrc.lo-lanes
#define SWAP32(a, b) asm("v_permlane32_swap_b32 %0, %1" : "+v"(a), "+v"(b))

static __device__ __forceinline__ unsigned short f2bf(float f) {
  union { float f; unsigned int u; } c; c.f = f;
  unsigned int r = (c.u + 0x7FFFu + ((c.u >> 16) & 1u)) >> 16;
  return (unsigned short)r;
}

static __device__ __forceinline__ void gld_lds16(const void* g, void* l) {
  __builtin_amdgcn_global_load_lds(
      (const __attribute__((address_space(1))) unsigned int*)g,
      (__attribute__((address_space(3))) unsigned int*)l, 16, 0, 0);
}

// ---------------- conversion kernels ----------------

__global__ void convert_x(const float* __restrict__ x, unsigned short* __restrict__ xb, int n4) {
  int i = blockIdx.x * blockDim.x + threadIdx.x;
  int stride = gridDim.x * blockDim.x;
  for (; i < n4; i += stride) {
    float4 v = ((const float4*)x)[i];
    ushort4v o;
    o[0] = f2bf(v.x); o[1] = f2bf(v.y); o[2] = f2bf(v.z); o[3] = f2bf(v.w);
    ((ushort4v*)xb)[i] = o;
  }
}

// All 4 weight transposes in one launch: W[k][n] fp32 -> WT[n][k] bf16.
__global__ void wtrans4(const float* __restrict__ Wq, const float* __restrict__ Wk,
                        const float* __restrict__ Wv, const float* __restrict__ Wo,
                        unsigned short* __restrict__ WT) {
  __shared__ float t[32][33];
  const int z = blockIdx.z;
  const float* W = (z == 0) ? Wq : (z == 1) ? Wk : (z == 2) ? Wv : Wo;
  unsigned short* dst = WT + (size_t)z * 589824;
  int tx = threadIdx.x, ty = threadIdx.y;
  int bx = blockIdx.x * 32, by = blockIdx.y * 32;
#pragma unroll
  for (int k = 0; k < 4; k++) t[ty + 8 * k][tx] = W[(size_t)(by + ty + 8 * k) * DM + bx + tx];
  __syncthreads();
#pragma unroll
  for (int k = 0; k < 4; k++)
    dst[(size_t)(bx + ty + 8 * k) * DM + by + tx] = f2bf(t[tx][ty + 8 * k]);
}

// ---------------- fused QKV GEMM ----------------
__global__ __launch_bounds__(256, 2) void gemm_qkv(const unsigned short* __restrict__ A,
                                                   const unsigned short* __restrict__ WT,
                                                   const float* __restrict__ bq,
                                                   const float* __restrict__ bk,
                                                   const float* __restrict__ bv,
                                                   unsigned short* __restrict__ Qo,
                                                   unsigned short* __restrict__ Ko,
                                                   unsigned short* __restrict__ Vo) {
  __shared__ unsigned short As[128 * 32];
  __shared__ unsigned short Bs[128 * 32];
  const int tid = threadIdx.x;
  const int wave = tid >> 6, lane = tid & 63;
  const int qd = lane >> 4, r = lane & 15;
  const int bm = blockIdx.x, bn = blockIdx.y;
  const int wr = (wave >> 1) * 64, wc = (wave & 1) * 64;

  f32x4 acc[4][4] = {};

  for (int k0 = 0; k0 < DM; k0 += 32) {
    __syncthreads();
#pragma unroll
    for (int p = 0; p < 2; p++) {
      int g = (wave * 2 + p) * 64 + lane;
      int row = g >> 2, ko = (g & 3) << 3;
      gld_lds16(A + (size_t)(bm * 128 + row) * DM + k0 + ko, &As[(wave * 2 + p) * 512]);
      gld_lds16(WT + (size_t)(bn * 128 + row) * DM + k0 + ko, &Bs[(wave * 2 + p) * 512]);
    }
    __syncthreads();

    short8 af[4], bfr[4];
#pragma unroll
    for (int mi = 0; mi < 4; mi++) af[mi] = *(const short8*)&As[(wr + mi * 16 + r) * 32 + qd * 8];
#pragma unroll
    for (int ni = 0; ni < 4; ni++) bfr[ni] = *(const short8*)&Bs[(wc + ni * 16 + r) * 32 + qd * 8];
#pragma unroll
    for (int mi = 0; mi < 4; mi++)
#pragma unroll
      for (int ni = 0; ni < 4; ni++) acc[mi][ni] = MFMA16(af[mi], bfr[ni], acc[mi][ni]);
  }

  const int seg = bn / 6;  // 0=Q 1=K 2=V
  const float* bias = (seg == 0) ? bq : (seg == 1) ? bk : bv;
  unsigned short* O = (seg == 0) ? Qo : (seg == 1) ? Ko : Vo;
  const float sc = (seg == 0) ? QSCALE : 1.0f;

#pragma unroll
  for (int ni = 0; ni < 4; ni++) {
    int nl = (bn - seg * 6) * 128 + wc + ni * 16 + r;  // 0..767 within segment
    float bvv = bias[nl];
    int h = nl >> 6, d = nl & 63;
#pragma unroll
    for (int mi = 0; mi < 4; mi++) {
      int m0 = bm * 128 + wr + mi * 16 + qd * 4;
      int b = m0 >> 12, s0m = m0 & 4095;
      f32x4 v = acc[mi][ni];
      if (seg == 2) {
        ushort4v pk;
        pk[0] = f2bf(v[0] + bvv); pk[1] = f2bf(v[1] + bvv);
        pk[2] = f2bf(v[2] + bvv); pk[3] = f2bf(v[3] + bvv);
        *(ushort4v*)&O[((size_t)((b * NH + h) * DHD + d)) * SS + s0m] = pk;
      } else {
#pragma unroll
        for (int i = 0; i < 4; i++)
          O[((size_t)((b * NH + h) * SS + s0m + i)) * DHD + d] = f2bf((v[i] + bvv) * sc);
      }
    }
  }
}

// ---------------- output projection GEMM (fp32 out) ----------------
__global__ __launch_bounds__(256, 2) void gemm_out(const unsigned short* __restrict__ A,
                                                   const unsigned short* __restrict__ BT,
                                                   const float* __restrict__ bias,
                                                   float* __restrict__ out) {
  __shared__ unsigned short As[128 * 32];
  __shared__ unsigned short Bs[128 * 32];
  const int tid = threadIdx.x;
  const int wave = tid >> 6, lane = tid & 63;
  const int qd = lane >> 4, r = lane & 15;
  const int bm = blockIdx.x, bn = blockIdx.y;
  const int wr = (wave >> 1) * 64, wc = (wave & 1) * 64;

  f32x4 acc[4][4] = {};

  for (int k0 = 0; k0 < DM; k0 += 32) {
    __syncthreads();
#pragma unroll
    for (int p = 0; p < 2; p++) {
      int g = (wave * 2 + p) * 64 + lane;
      int row = g >> 2, ko = (g & 3) << 3;
      gld_lds16(A + (size_t)(bm * 128 + row) * DM + k0 + ko, &As[(wave * 2 + p) * 512]);
      gld_lds16(BT + (size_t)(bn * 128 + row) * DM + k0 + ko, &Bs[(wave * 2 + p) * 512]);
    }
    __syncthreads();

    short8 af[4], bfr[4];
#pragma unroll
    for (int mi = 0; mi < 4; mi++) af[mi] = *(const short8*)&As[(wr + mi * 16 + r) * 32 + qd * 8];
#pragma unroll
    for (int ni = 0; ni < 4; ni++) bfr[ni] = *(const short8*)&Bs[(wc + ni * 16 + r) * 32 + qd * 8];
#pragma unroll
    for (int mi = 0; mi < 4; mi++)
#pragma unroll
      for (int ni = 0; ni < 4; ni++) acc[mi][ni] = MFMA16(af[mi], bfr[ni], acc[mi][ni]);
  }

#pragma unroll
  for (int ni = 0; ni < 4; ni++) {
    int n = bn * 128 + wc + ni * 16 + r;
    float bvv = bias[n];
#pragma unroll
    for (int mi = 0; mi < 4; mi++) {
      int m0 = bm * 128 + wr + mi * 16 + qd * 4;
      f32x4 v = acc[mi][ni];
#pragma unroll
      for (int i = 0; i < 4; i++) out[(size_t)(m0 + i) * DM + n] = v[i] + bvv;
    }
  }
}

// ---------------- flash attention v11 = r12 attn10 + const-folded LDS addressing ----------------
// Identity transform of r12: (1) the only 4 distinct per-lane LDS byte addresses
// (adr0..3) hoisted out of the loop (QK and PV provably share them; row1 = +4096
// folds into offset:imm); (2) main loop 3x-unrolled with COMPILE-TIME buffer byte
// offsets (buf k: 0/16384/32768; V region +8192) instead of rotating pointers.
// Every LDS read becomes ds_read_b128 vaddr=adrX offset:const. Math byte-identical.
__global__ __launch_bounds__(256, 3) void attn11(const unsigned short* __restrict__ Q,
                                                 const unsigned short* __restrict__ K,
                                                 const unsigned short* __restrict__ VT,
                                                 unsigned short* __restrict__ ctx) {
  __shared__ __align__(16) unsigned short sh[24576];  // 3 bufs x (K 8KB + V 8KB) = 49152 B
  const int tid = threadIdx.x;
  const int w = tid >> 6, lane = tid & 63;
  const int ln = lane & 31, hi = lane >> 5;
  const int qt = blockIdx.x, h = blockIdx.y, b = blockIdx.z;
  const int bh = b * NH + h;
  const unsigned short* Qh = Q + (size_t)bh * SS * DHD;
  const unsigned short* Kh = K + (size_t)bh * SS * DHD;
  const unsigned short* Vh = VT + (size_t)bh * DHD * SS;
  const int q0 = qt * 128 + w * 32;

  // stage tile (64 keys) into buffer at compile-time byte offset BUF
  auto stage = [&](int kv, int BUF) {
#pragma unroll
    for (int p = 0; p < 2; p++) {
      int g = ((w << 1) + p) * 64 + lane;
      int row = g >> 3, c = g & 7;
      int cs = (c ^ (row & 7)) << 3;
      gld_lds16(Kh + (size_t)(kv + row) * DHD + cs,
                (char*)sh + BUF + (((w << 1) + p) << 10));
      gld_lds16(Vh + (size_t)row * SS + kv + cs,
                (char*)sh + BUF + 8192 + (((w << 1) + p) << 10));
    }
  };

  // Q B-fragments: lane holds Q[q=ln][dh = kc*16 + hi*8 + j]
  short8 qf[4];
#pragma unroll
  for (int kc = 0; kc < 4; kc++)
    qf[kc] = *(const short8*)&Qh[(size_t)(q0 + ln) * DHD + kc * 16 + hi * 8];
#pragma unroll
  for (int kc = 0; kc < 4; kc++) asm volatile("" : "+v"(qf[kc]));

  const f32x16 fzero = {};

  // the 4 distinct per-lane LDS byte addresses (row ln; row 32+ln = +4096 imm)
  const int lnm = ln & 7;
  const int adr0 = (ln << 7) + (((0 + hi) ^ lnm) << 4);
  const int adr1 = (ln << 7) + (((2 + hi) ^ lnm) << 4);
  const int adr2 = (ln << 7) + (((4 + hi) ^ lnm) << 4);
  const int adr3 = (ln << 7) + (((6 + hi) ^ lnm) << 4);

#define LDS8(off) (*(const short8*)((const char*)sh + (off)))

  float lrun = 0.f;  // per half-lane partial; combined at epilogue
  f32x16 o0 = {}, o1 = {};
  f32x16 s0, s1;
  union PF { uint4v u; short8 s; };
  PF pf0, pf1, pf2, pf3;

#define QK(KBUF)                                                        \
  do {                                                                  \
    __builtin_amdgcn_s_setprio(1);                                      \
    s0 = MFMA32(LDS8((KBUF) + adr0), qf[0], fzero);                     \
    s1 = MFMA32(LDS8((KBUF) + adr0 + 4096), qf[0], fzero);              \
    s0 = MFMA32(LDS8((KBUF) + adr1), qf[1], s0);                        \
    s1 = MFMA32(LDS8((KBUF) + adr1 + 4096), qf[1], s1);                 \
    s0 = MFMA32(LDS8((KBUF) + adr2), qf[2], s0);                        \
    s1 = MFMA32(LDS8((KBUF) + adr2 + 4096), qf[2], s1);                 \
    s0 = MFMA32(LDS8((KBUF) + adr3), qf[3], s0);                        \
    s1 = MFMA32(LDS8((KBUF) + adr3 + 4096), qf[3], s1);                 \
    __builtin_amdgcn_s_setprio(0);                                      \
  } while (0)

#define PV(VBUF)                                                        \
  do {                                                                  \
    __builtin_amdgcn_s_setprio(1);                                      \
    o0 = MFMA32(LDS8((VBUF) + adr0), pf0.s, o0);                        \
    o1 = MFMA32(LDS8((VBUF) + adr0 + 4096), pf0.s, o1);                 \
    o0 = MFMA32(LDS8((VBUF) + adr1), pf1.s, o0);                        \
    o1 = MFMA32(LDS8((VBUF) + adr1 + 4096), pf1.s, o1);                 \
    o0 = MFMA32(LDS8((VBUF) + adr2), pf2.s, o0);                        \
    o1 = MFMA32(LDS8((VBUF) + adr2 + 4096), pf2.s, o1);                 \
    o0 = MFMA32(LDS8((VBUF) + adr3), pf3.s, o0);                        \
    o1 = MFMA32(LDS8((VBUF) + adr3 + 4096), pf3.s, o1);                 \
    __builtin_amdgcn_s_setprio(0);                                      \
  } while (0)

  // no-max softmax: p = exp2(s) directly; sum into lrun; pack P -> bf16 B-frags
  auto sm = [&]() {
#pragma unroll
    for (int i = 0; i < 16; i++) {
      s0[i] = __builtin_amdgcn_exp2f(s0[i]);
      s1[i] = __builtin_amdgcn_exp2f(s1[i]);
    }
    float a8[8];
#pragma unroll
    for (int i = 0; i < 8; i++) a8[i] = (s0[i] + s0[i + 8]) + (s1[i] + s1[i + 8]);
#pragma unroll
    for (int i = 0; i < 4; i++) a8[i] += a8[i + 4];
    lrun += (a8[0] + a8[1]) + (a8[2] + a8[3]);
    {
      unsigned int w0, w1, w2, w3, w4, w5, w6, w7;
      CVTPK(w0, s0[0], s0[1]);   CVTPK(w1, s0[2], s0[3]);
      CVTPK(w2, s0[4], s0[5]);   CVTPK(w3, s0[6], s0[7]);
      CVTPK(w4, s0[8], s0[9]);   CVTPK(w5, s0[10], s0[11]);
      CVTPK(w6, s0[12], s0[13]); CVTPK(w7, s0[14], s0[15]);
      SWAP32(w0, w2); SWAP32(w1, w3); SWAP32(w4, w6); SWAP32(w5, w7);
      pf0.u = (uint4v){w0, w1, w2, w3};
      pf1.u = (uint4v){w4, w5, w6, w7};
    }
    {
      unsigned int w0, w1, w2, w3, w4, w5, w6, w7;
      CVTPK(w0, s1[0], s1[1]);   CVTPK(w1, s1[2], s1[3]);
      CVTPK(w2, s1[4], s1[5]);   CVTPK(w3, s1[6], s1[7]);
      CVTPK(w4, s1[8], s1[9]);   CVTPK(w5, s1[10], s1[11]);
      CVTPK(w6, s1[12], s1[13]); CVTPK(w7, s1[14], s1[15]);
      SWAP32(w0, w2); SWAP32(w1, w3); SWAP32(w4, w6); SWAP32(w5, w7);
      pf2.u = (uint4v){w0, w1, w2, w3};
      pf3.u = (uint4v){w4, w5, w6, w7};
    }
  };

// one pipeline step: wait, barrier, stage tile T+1 into BNXT, QK(T), PV(T-1), softmax
#define BODY(T, KCUR, VPREV, BNXT)                       \
  do {                                                   \
    asm volatile("s_waitcnt vmcnt(0)" ::: "memory");     \
    __builtin_amdgcn_s_barrier();                        \
    stage(((T) + 1) << 6, (BNXT));                       \
    QK(KCUR);                                            \
    PV(VPREV);                                           \
    sm();                                                \
  } while (0)

  // tile τ lives in buf[τ%3]: buf bytes 0 / 16384 / 32768; V region = +8192
  stage(0, 0);

  // ---- peeled iteration 0 ----
  asm volatile("s_waitcnt vmcnt(0)" ::: "memory");
  __builtin_amdgcn_s_barrier();
  stage(64, 16384);
  QK(0);
  sm();

  // ---- main loop t = 1..60 (20 iterations x 3 bodies, buffer offsets compile-time) ----
  for (int tt = 1; tt < 61; tt += 3) {
    BODY(tt, 16384, 0 + 8192, 32768);       // t%3==1: K in buf1, V(t-1) in buf0
    BODY(tt + 1, 32768, 16384 + 8192, 0);   // t%3==2: K in buf2, V(t-1) in buf1
    BODY(tt + 2, 0, 32768 + 8192, 16384);   // t%3==0: K in buf0, V(t-1) in buf2
  }
  // ---- peeled t = 61, 62, 63 ----
  BODY(61, 16384, 0 + 8192, 32768);
  BODY(62, 32768, 16384 + 8192, 0);
  {  // t = 63: no stage
    asm volatile("s_waitcnt vmcnt(0)" ::: "memory");
    __builtin_amdgcn_s_barrier();
    QK(0);
    PV(32768 + 8192);
    sm();
  }
  // tail: PV of tile 63 (its V is in buf0)
  PV(0 + 8192);

  // epilogue: combine half-lane l partials once, then O^T[d][q] -> ctx[b*S+sq][h*64+d]
  float l = lrun + __shfl_xor(lrun, 32);
  float inv = 1.0f / l;
  int sq = q0 + ln;
  unsigned short* cp = ctx + ((size_t)(b * SS + sq)) * DM + h * DHD;
#pragma unroll
  for (int q2 = 0; q2 < 4; q2++) {
    unsigned int pl, ph;
    CVTPK(pl, o0[q2 * 4 + 0] * inv, o0[q2 * 4 + 1] * inv);
    CVTPK(ph, o0[q2 * 4 + 2] * inv, o0[q2 * 4 + 3] * inv);
    uint2 st0; st0.x = pl; st0.y = ph;
    *(uint2*)(cp + q2 * 8 + hi * 4) = st0;
    CVTPK(pl, o1[q2 * 4 + 0] * inv, o1[q2 * 4 + 1] * inv);
    CVTPK(ph, o1[q2 * 4 + 2] * inv, o1[q2 * 4 + 3] * inv);
    uint2 st1; st1.x = pl; st1.y = ph;
    *(uint2*)(cp + 32 + q2 * 8 + hi * 4) = st1;
  }
#undef LDS8
#undef QK
#undef PV
#undef BODY
}

// ---------------- launcher ----------------

extern "C" void kernel_launch(void* const* d_in, const int* in_sizes, int n_in,
                              void* d_out, int out_size, void* d_ws, size_t ws_size,
                              hipStream_t stream) {
  const float* hs = (const float*)d_in[0];
  const float* Wq = (const float*)d_in[1];
  const float* bq = (const float*)d_in[2];
  const float* Wk = (const float*)d_in[3];
  const float* bk = (const float*)d_in[4];
  const float* Wv = (const float*)d_in[5];
  const float* bv = (const float*)d_in[6];
  const float* Wo = (const float*)d_in[7];
  const float* bo = (const float*)d_in[8];

  char* ws = (char*)d_ws;
  unsigned short* Xbf = (unsigned short*)(ws + 0);           // 12.58 MB; later reused as ctx
  unsigned short* WqkvT = (unsigned short*)(ws + 12582912);  // 2304x768 + 768x768 bf16 (Wo contiguous)
  unsigned short* Qb = (unsigned short*)(ws + 17301504);     // 12.58 MB
  unsigned short* Kb = (unsigned short*)(ws + 29884416);     // 12.58 MB
  unsigned short* Vt = (unsigned short*)(ws + 42467328);     // 12.58 MB (end ~55.05 MB)
  unsigned short* WoT = WqkvT + 1769472;                     // = ws + 16121856

  convert_x<<<2048, 256, 0, stream>>>(hs, Xbf, MTOK * DM / 4);
  wtrans4<<<dim3(24, 24, 4), dim3(32, 8), 0, stream>>>(Wq, Wk, Wv, Wo, WqkvT);

  gemm_qkv<<<dim3(64, 18), 256, 0, stream>>>(Xbf, WqkvT, bq, bk, bv, Qb, Kb, Vt);

  attn11<<<dim3(32, NH, NB), 256, 0, stream>>>(Qb, Kb, Vt, Xbf);

  gemm_out<<<dim3(64, 6), 256, 0, stream>>>(Xbf, WoT, bo, (float*)d_out);
}

// Round 14
// 198.074 us; speedup vs baseline: 1.3440x; 1.3440x over previous
//
#include <hip/hip_runtime.h>
#include <hip/hip_bf16.h>
#include <stdint.h>

// Problem constants
#define NH 12
#define DHD 64
#define DM 768
#define NB 2
#define SS 4096
#define MTOK 8192  // NB*SS

typedef __attribute__((ext_vector_type(8))) short short8;
typedef __attribute__((ext_vector_type(4))) float f32x4;
typedef __attribute__((ext_vector_type(16))) float f32x16;
typedef __attribute__((ext_vector_type(4))) unsigned short ushort4v;
typedef __attribute__((ext_vector_type(4))) unsigned int uint4v;

#define MFMA16(a, b, c) __builtin_amdgcn_mfma_f32_16x16x32_bf16(a, b, c, 0, 0, 0)
#define MFMA32(a, b, c) __builtin_amdgcn_mfma_f32_32x32x16_bf16(a, b, c, 0, 0, 0)

// Q is pre-scaled by SCALE*log2(e) so softmax works in exp2 domain.
#define QSCALE 0.18033688f  // 0.125 * 1.4426950408889634

#define CVTPK(d, a, b) asm("v_cvt_pk_bf16_f32 %0, %1, %2" : "=v"(d) : "v"(a), "v"(b))
// v_permlane32_swap_b32 vdst, vsrc : vdst.hi-lanes <-> vsrc.lo-lanes
#define SWAP32(a, b) asm("v_permlane32_swap_b32 %0, %1" : "+v"(a), "+v"(b))

static __device__ __forceinline__ unsigned short f2bf(float f) {
  union { float f; unsigned int u; } c; c.f = f;
  unsigned int r = (c.u + 0x7FFFu + ((c.u >> 16) & 1u)) >> 16;
  return (unsigned short)r;
}

static __device__ __forceinline__ void gld_lds16(const void* g, void* l) {
  __builtin_amdgcn_global_load_lds(
      (const __attribute__((address_space(1))) unsigned int*)g,
      (__attribute__((address_space(3))) unsigned int*)l, 16, 0, 0);
}

// ---------------- fused prep kernel: X fp32->bf16 convert + 4 weight transposes ----------------
// Blocks 0..2047: grid-stride convert of X (1.57M float4s).
// Blocks 2048..4351: one 32x32 transpose tile each (2304 tiles = 24x24x4 weights).
__global__ void prep(const float* __restrict__ x, unsigned short* __restrict__ xb,
                     const float* __restrict__ Wq, const float* __restrict__ Wk,
                     const float* __restrict__ Wv, const float* __restrict__ Wo,
                     unsigned short* __restrict__ WT) {
  __shared__ float t[32][33];
  const int bid = blockIdx.x;
  if (bid < 2048) {
    const int n4 = MTOK * DM / 4;
    int i = bid * 256 + threadIdx.x;
    int stride = 2048 * 256;
    for (; i < n4; i += stride) {
      float4 v = ((const float4*)x)[i];
      ushort4v o;
      o[0] = f2bf(v.x); o[1] = f2bf(v.y); o[2] = f2bf(v.z); o[3] = f2bf(v.w);
      ((ushort4v*)xb)[i] = o;
    }
  } else {
    int tile = bid - 2048;           // 0..2303
    int z = tile / 576;              // weight index
    int rem = tile - z * 576;        // 0..575
    int by = (rem / 24) * 32, bx = (rem % 24) * 32;
    const float* W = (z == 0) ? Wq : (z == 1) ? Wk : (z == 2) ? Wv : Wo;
    unsigned short* dst = WT + (size_t)z * 589824;
    int tx = threadIdx.x & 31, ty = threadIdx.x >> 5;  // 32x8
#pragma unroll
    for (int k = 0; k < 4; k++) t[ty + 8 * k][tx] = W[(size_t)(by + ty + 8 * k) * DM + bx + tx];
    __syncthreads();
#pragma unroll
    for (int k = 0; k < 4; k++)
      dst[(size_t)(bx + ty + 8 * k) * DM + by + tx] = f2bf(t[tx][ty + 8 * k]);
  }
}

// ---------------- fused QKV GEMM ----------------
// C[8192][2304] = X[8192][768] @ WqkvT^T + bias, epilogue routed by bn:
//   bn 0-5  -> Q bf16 [(b*12+h)*4096+s][64] scaled by QSCALE
//   bn 6-11 -> K bf16 same layout
//   bn 12-17-> V bf16 transposed [(b*12+h)*64+d][4096]
// No __launch_bounds__: m97 precedent (same structure) -> ~164 VGPR, 3 blocks/CU.
__global__ void gemm_qkv(const unsigned short* __restrict__ A,
                         const unsigned short* __restrict__ WT,
                         const float* __restrict__ bq,
                         const float* __restrict__ bk,
                         const float* __restrict__ bv,
                         unsigned short* __restrict__ Qo,
                         unsigned short* __restrict__ Ko,
                         unsigned short* __restrict__ Vo) {
  __shared__ unsigned short As[128 * 32];
  __shared__ unsigned short Bs[128 * 32];
  const int tid = threadIdx.x;
  const int wave = tid >> 6, lane = tid & 63;
  const int qd = lane >> 4, r = lane & 15;
  const int bm = blockIdx.x, bn = blockIdx.y;
  const int wr = (wave >> 1) * 64, wc = (wave & 1) * 64;

  f32x4 acc[4][4] = {};

  for (int k0 = 0; k0 < DM; k0 += 32) {
    __syncthreads();
#pragma unroll
    for (int p = 0; p < 2; p++) {
      int g = (wave * 2 + p) * 64 + lane;
      int row = g >> 2, ko = (g & 3) << 3;
      gld_lds16(A + (size_t)(bm * 128 + row) * DM + k0 + ko, &As[(wave * 2 + p) * 512]);
      gld_lds16(WT + (size_t)(bn * 128 + row) * DM + k0 + ko, &Bs[(wave * 2 + p) * 512]);
    }
    __syncthreads();

    short8 af[4], bfr[4];
#pragma unroll
    for (int mi = 0; mi < 4; mi++) af[mi] = *(const short8*)&As[(wr + mi * 16 + r) * 32 + qd * 8];
#pragma unroll
    for (int ni = 0; ni < 4; ni++) bfr[ni] = *(const short8*)&Bs[(wc + ni * 16 + r) * 32 + qd * 8];
#pragma unroll
    for (int mi = 0; mi < 4; mi++)
#pragma unroll
      for (int ni = 0; ni < 4; ni++) acc[mi][ni] = MFMA16(af[mi], bfr[ni], acc[mi][ni]);
  }

  const int seg = bn / 6;  // 0=Q 1=K 2=V
  const float* bias = (seg == 0) ? bq : (seg == 1) ? bk : bv;
  unsigned short* O = (seg == 0) ? Qo : (seg == 1) ? Ko : Vo;
  const float sc = (seg == 0) ? QSCALE : 1.0f;

#pragma unroll
  for (int ni = 0; ni < 4; ni++) {
    int nl = (bn - seg * 6) * 128 + wc + ni * 16 + r;  // 0..767 within segment
    float bvv = bias[nl];
    int h = nl >> 6, d = nl & 63;
#pragma unroll
    for (int mi = 0; mi < 4; mi++) {
      int m0 = bm * 128 + wr + mi * 16 + qd * 4;
      int b = m0 >> 12, s0m = m0 & 4095;
      f32x4 v = acc[mi][ni];
      if (seg == 2) {
        ushort4v pk;
        pk[0] = f2bf(v[0] + bvv); pk[1] = f2bf(v[1] + bvv);
        pk[2] = f2bf(v[2] + bvv); pk[3] = f2bf(v[3] + bvv);
        *(ushort4v*)&O[((size_t)((b * NH + h) * DHD + d)) * SS + s0m] = pk;
      } else {
#pragma unroll
        for (int i = 0; i < 4; i++)
          O[((size_t)((b * NH + h) * SS + s0m + i)) * DHD + d] = f2bf((v[i] + bvv) * sc);
      }
    }
  }
}

// ---------------- output projection GEMM (fp32 out) ----------------
__global__ void gemm_out(const unsigned short* __restrict__ A,
                         const unsigned short* __restrict__ BT,
                         const float* __restrict__ bias,
                         float* __restrict__ out) {
  __shared__ unsigned short As[128 * 32];
  __shared__ unsigned short Bs[128 * 32];
  const int tid = threadIdx.x;
  const int wave = tid >> 6, lane = tid & 63;
  const int qd = lane >> 4, r = lane & 15;
  const int bm = blockIdx.x, bn = blockIdx.y;
  const int wr = (wave >> 1) * 64, wc = (wave & 1) * 64;

  f32x4 acc[4][4] = {};

  for (int k0 = 0; k0 < DM; k0 += 32) {
    __syncthreads();
#pragma unroll
    for (int p = 0; p < 2; p++) {
      int g = (wave * 2 + p) * 64 + lane;
      int row = g >> 2, ko = (g & 3) << 3;
      gld_lds16(A + (size_t)(bm * 128 + row) * DM + k0 + ko, &As[(wave * 2 + p) * 512]);
      gld_lds16(BT + (size_t)(bn * 128 + row) * DM + k0 + ko, &Bs[(wave * 2 + p) * 512]);
    }
    __syncthreads();

    short8 af[4], bfr[4];
#pragma unroll
    for (int mi = 0; mi < 4; mi++) af[mi] = *(const short8*)&As[(wr + mi * 16 + r) * 32 + qd * 8];
#pragma unroll
    for (int ni = 0; ni < 4; ni++) bfr[ni] = *(const short8*)&Bs[(wc + ni * 16 + r) * 32 + qd * 8];
#pragma unroll
    for (int mi = 0; mi < 4; mi++)
#pragma unroll
      for (int ni = 0; ni < 4; ni++) acc[mi][ni] = MFMA16(af[mi], bfr[ni], acc[mi][ni]);
  }

#pragma unroll
  for (int ni = 0; ni < 4; ni++) {
    int n = bn * 128 + wc + ni * 16 + r;
    float bvv = bias[n];
#pragma unroll
    for (int mi = 0; mi < 4; mi++) {
      int m0 = bm * 128 + wr + mi * 16 + qd * 4;
      f32x4 v = acc[mi][ni];
#pragma unroll
      for (int i = 0; i < 4; i++) out[(size_t)(m0 + i) * DM + n] = v[i] + bvv;
    }
  }
}

// ---------------- flash attention v10 (r12, verbatim): no-max softmax, deferred-PV ----------------
// r13's const-offset unroll REVERTED (spilled: VGPR 84, 256MB scratch writes).
__global__ __launch_bounds__(256, 3) void attn10(const unsigned short* __restrict__ Q,
                                                 const unsigned short* __restrict__ K,
                                                 const unsigned short* __restrict__ VT,
                                                 unsigned short* __restrict__ ctx) {
  __shared__ __align__(16) unsigned short sh[24576];  // 3 bufs x (K 4096 + V 4096) = 49152 B
  const int tid = threadIdx.x;
  const int w = tid >> 6, lane = tid & 63;
  const int ln = lane & 31, hi = lane >> 5;
  const int qt = blockIdx.x, h = blockIdx.y, b = blockIdx.z;
  const int bh = b * NH + h;
  const unsigned short* Qh = Q + (size_t)bh * SS * DHD;
  const unsigned short* Kh = K + (size_t)bh * SS * DHD;
  const unsigned short* Vh = VT + (size_t)bh * DHD * SS;
  const int q0 = qt * 128 + w * 32;

  // stage tile (64 keys): K 8KB + V 8KB, XOR-swizzled via pre-swizzled global src
  auto stage = [&](int kv, unsigned short* base) {
#pragma unroll
    for (int p = 0; p < 2; p++) {
      int g = ((w << 1) + p) * 64 + lane;
      int row = g >> 3, c = g & 7;
      int cs = (c ^ (row & 7)) << 3;
      gld_lds16(Kh + (size_t)(kv + row) * DHD + cs, base + (((w << 1) + p) << 9));
      gld_lds16(Vh + (size_t)row * SS + kv + cs, base + 4096 + (((w << 1) + p) << 9));
    }
  };

  // Q B-fragments: lane holds Q[q=ln][dh = kc*16 + hi*8 + j]
  short8 qf[4];
#pragma unroll
  for (int kc = 0; kc < 4; kc++)
    qf[kc] = *(const short8*)&Qh[(size_t)(q0 + ln) * DHD + kc * 16 + hi * 8];
#pragma unroll
  for (int kc = 0; kc < 4; kc++) asm volatile("" : "+v"(qf[kc]));

  // hoisted zero accumulator seed (plain const, SSA identity — validated r11)
  const f32x16 fzero = {};

  unsigned short* bprev = sh + 16384;
  unsigned short* bcur = sh;
  unsigned short* bnxt = sh + 8192;

  stage(0, bcur);

  float lrun = 0.f;  // per half-lane partial (this lane's 32 of 64 keys); combined at epilogue
  f32x16 o0 = {}, o1 = {};
  f32x16 s0, s1;
  union PF { uint4v u; short8 s; };
  PF pf0, pf1, pf2, pf3;

  // QK^T into s0,s1 from K buffer (kc=0 seeds from hoisted zero)
  auto qk = [&](const unsigned short* Kb) {
    __builtin_amdgcn_s_setprio(1);
    {
      int sl = (hi ^ (ln & 7)) << 3;  // kc = 0
      s0 = MFMA32(*(const short8*)&Kb[(ln << 6) + sl], qf[0], fzero);
      s1 = MFMA32(*(const short8*)&Kb[((32 + ln) << 6) + sl], qf[0], fzero);
    }
#pragma unroll
    for (int kc = 1; kc < 4; kc++) {
      int sl = (((kc << 1) + hi) ^ (ln & 7)) << 3;
      s0 = MFMA32(*(const short8*)&Kb[(ln << 6) + sl], qf[kc], s0);
      s1 = MFMA32(*(const short8*)&Kb[((32 + ln) << 6) + sl], qf[kc], s1);
    }
    __builtin_amdgcn_s_setprio(0);
  };

  // accumulate PV of the PREVIOUS tile (pf*, V in Vb) — pure MFMA, no rescale ever
  auto pv = [&](const unsigned short* Vb) {
    __builtin_amdgcn_s_setprio(1);
    {
      int sl0 = ((0 + hi) ^ (ln & 7)) << 3;
      int sl1 = ((2 + hi) ^ (ln & 7)) << 3;
      o0 = MFMA32(*(const short8*)&Vb[(ln << 6) + sl0], pf0.s, o0);
      o1 = MFMA32(*(const short8*)&Vb[((32 + ln) << 6) + sl0], pf0.s, o1);
      o0 = MFMA32(*(const short8*)&Vb[(ln << 6) + sl1], pf1.s, o0);
      o1 = MFMA32(*(const short8*)&Vb[((32 + ln) << 6) + sl1], pf1.s, o1);
    }
    {
      int sl0 = ((4 + hi) ^ (ln & 7)) << 3;
      int sl1 = ((6 + hi) ^ (ln & 7)) << 3;
      o0 = MFMA32(*(const short8*)&Vb[(ln << 6) + sl0], pf2.s, o0);
      o1 = MFMA32(*(const short8*)&Vb[((32 + ln) << 6) + sl0], pf2.s, o1);
      o0 = MFMA32(*(const short8*)&Vb[(ln << 6) + sl1], pf3.s, o0);
      o1 = MFMA32(*(const short8*)&Vb[((32 + ln) << 6) + sl1], pf3.s, o1);
    }
    __builtin_amdgcn_s_setprio(0);
  };

  // no-max softmax: p = exp2(s) directly (Q pre-scaled into exp2 domain), sum, pack
  auto sm = [&]() {
#pragma unroll
    for (int i = 0; i < 16; i++) {
      s0[i] = __builtin_amdgcn_exp2f(s0[i]);
      s1[i] = __builtin_amdgcn_exp2f(s1[i]);
    }
    float a8[8];
#pragma unroll
    for (int i = 0; i < 8; i++) a8[i] = (s0[i] + s0[i + 8]) + (s1[i] + s1[i + 8]);
#pragma unroll
    for (int i = 0; i < 4; i++) a8[i] += a8[i + 4];
    lrun += (a8[0] + a8[1]) + (a8[2] + a8[3]);
    // P -> bf16 B-frags (cvt_pk + permlane32_swap). s reg r holds key (r&3)+8*(r>>2)+4*hi.
    {
      unsigned int w0, w1, w2, w3, w4, w5, w6, w7;
      CVTPK(w0, s0[0], s0[1]);   CVTPK(w1, s0[2], s0[3]);
      CVTPK(w2, s0[4], s0[5]);   CVTPK(w3, s0[6], s0[7]);
      CVTPK(w4, s0[8], s0[9]);   CVTPK(w5, s0[10], s0[11]);
      CVTPK(w6, s0[12], s0[13]); CVTPK(w7, s0[14], s0[15]);
      SWAP32(w0, w2); SWAP32(w1, w3); SWAP32(w4, w6); SWAP32(w5, w7);
      pf0.u = (uint4v){w0, w1, w2, w3};
      pf1.u = (uint4v){w4, w5, w6, w7};
    }
    {
      unsigned int w0, w1, w2, w3, w4, w5, w6, w7;
      CVTPK(w0, s1[0], s1[1]);   CVTPK(w1, s1[2], s1[3]);
      CVTPK(w2, s1[4], s1[5]);   CVTPK(w3, s1[6], s1[7]);
      CVTPK(w4, s1[8], s1[9]);   CVTPK(w5, s1[10], s1[11]);
      CVTPK(w6, s1[12], s1[13]); CVTPK(w7, s1[14], s1[15]);
      SWAP32(w0, w2); SWAP32(w1, w3); SWAP32(w4, w6); SWAP32(w5, w7);
      pf2.u = (uint4v){w0, w1, w2, w3};
      pf3.u = (uint4v){w4, w5, w6, w7};
    }
  };

  // ---- peeled iteration 0 ----
  asm volatile("s_waitcnt vmcnt(0)" ::: "memory");
  __builtin_amdgcn_s_barrier();
  stage(64, bnxt);
  qk(bcur);
  sm();
  { unsigned short* t = bprev; bprev = bcur; bcur = bnxt; bnxt = t; }

  // ---- main loop t = 1..63 ----
  for (int t = 1; t < SS / 64; t++) {
    asm volatile("s_waitcnt vmcnt(0)" ::: "memory");
    __builtin_amdgcn_s_barrier();
    if (t < SS / 64 - 1) stage((t + 1) << 6, bnxt);
    qk(bcur);
    pv(bprev + 4096);
    sm();
    { unsigned short* tp = bprev; bprev = bcur; bcur = bnxt; bnxt = tp; }
  }

  // tail: PV of last tile (its V is in bprev after final rotation)
  pv(bprev + 4096);

  // epilogue: combine half-lane l partials once, then O^T[d][q] -> ctx[b*S+sq][h*64+d]
  float l = lrun + __shfl_xor(lrun, 32);
  float inv = 1.0f / l;
  int sq = q0 + ln;
  unsigned short* cp = ctx + ((size_t)(b * SS + sq)) * DM + h * DHD;
#pragma unroll
  for (int q2 = 0; q2 < 4; q2++) {
    unsigned int pl, ph;
    CVTPK(pl, o0[q2 * 4 + 0] * inv, o0[q2 * 4 + 1] * inv);
    CVTPK(ph, o0[q2 * 4 + 2] * inv, o0[q2 * 4 + 3] * inv);
    uint2 st0; st0.x = pl; st0.y = ph;
    *(uint2*)(cp + q2 * 8 + hi * 4) = st0;
    CVTPK(pl, o1[q2 * 4 + 0] * inv, o1[q2 * 4 + 1] * inv);
    CVTPK(ph, o1[q2 * 4 + 2] * inv, o1[q2 * 4 + 3] * inv);
    uint2 st1; st1.x = pl; st1.y = ph;
    *(uint2*)(cp + 32 + q2 * 8 + hi * 4) = st1;
  }
}

// ---------------- launcher ----------------

extern "C" void kernel_launch(void* const* d_in, const int* in_sizes, int n_in,
                              void* d_out, int out_size, void* d_ws, size_t ws_size,
                              hipStream_t stream) {
  const float* hs = (const float*)d_in[0];
  const float* Wq = (const float*)d_in[1];
  const float* bq = (const float*)d_in[2];
  const float* Wk = (const float*)d_in[3];
  const float* bk = (const float*)d_in[4];
  const float* Wv = (const float*)d_in[5];
  const float* bv = (const float*)d_in[6];
  const float* Wo = (const float*)d_in[7];
  const float* bo = (const float*)d_in[8];

  char* ws = (char*)d_ws;
  unsigned short* Xbf = (unsigned short*)(ws + 0);           // 12.58 MB; later reused as ctx
  unsigned short* WqkvT = (unsigned short*)(ws + 12582912);  // 2304x768 + 768x768 bf16 (Wo contiguous)
  unsigned short* Qb = (unsigned short*)(ws + 17301504);     // 12.58 MB
  unsigned short* Kb = (unsigned short*)(ws + 29884416);     // 12.58 MB
  unsigned short* Vt = (unsigned short*)(ws + 42467328);     // 12.58 MB (end ~55.05 MB)
  unsigned short* WoT = WqkvT + 1769472;                     // = ws + 16121856

  prep<<<4352, 256, 0, stream>>>(hs, Xbf, Wq, Wk, Wv, Wo, WqkvT);

  gemm_qkv<<<dim3(64, 18), 256, 0, stream>>>(Xbf, WqkvT, bq, bk, bv, Qb, Kb, Vt);

  attn10<<<dim3(32, NH, NB), 256, 0, stream>>>(Qb, Kb, Vt, Xbf);

  gemm_out<<<dim3(64, 6), 256, 0, stream>>>(Xbf, WoT, bo, (float*)d_out);
}